// Round 3
// baseline (298.268 us; speedup 1.0000x reference)
//
#include <hip/hip_runtime.h>

#define NDATA 100000
#define KP1 16385            // NCE_K + 1
#define BSZ 64
#define PTOT (BSZ * KP1)     // 1,048,640
#define NCHUNKS 6250         // NDATA / 16 (exact)
#define INV_T (1.0f / 0.07f)
#define OVF_CAP 256          // per-maskbuild-block dup capacity (expect ~80, 20 sigma)
#define NMBLK 1024           // maskbuild blocks = 64 b x 16 parts

typedef short short8 __attribute__((ext_vector_type(8)));
typedef float f32x4 __attribute__((ext_vector_type(4)));

__device__ __forceinline__ float wave_reduce64(float v) {
    #pragma unroll
    for (int off = 32; off >= 1; off >>= 1) v += __shfl_xor(v, off);
    return v;
}

__device__ __forceinline__ float group_reduce16(float v) {
    v += __shfl_xor(v, 8); v += __shfl_xor(v, 4);
    v += __shfl_xor(v, 2); v += __shfl_xor(v, 1);
    return v;
}

__device__ __forceinline__ unsigned short f2bf(float f) {
    unsigned u = __float_as_uint(f);
    u += 0x7FFFu + ((u >> 16) & 1u);   // round-to-nearest-even
    return (unsigned short)(u >> 16);
}

// bf16-round a float and return it as float (matches MFMA input rounding)
__device__ __forceinline__ float bfm(float x) {
    return __uint_as_float(((unsigned)f2bf(x)) << 16);
}

__device__ __forceinline__ short8 pack_bf16(float4 lo, float4 hi) {
    short8 r;
    r[0] = (short)f2bf(lo.x); r[1] = (short)f2bf(lo.y);
    r[2] = (short)f2bf(lo.z); r[3] = (short)f2bf(lo.w);
    r[4] = (short)f2bf(hi.x); r[5] = (short)f2bf(hi.y);
    r[6] = (short)f2bf(hi.z); r[7] = (short)f2bf(hi.w);
    return r;
}

__device__ __forceinline__ float dot4(float4 a, float4 b, float acc) {
    acc = fmaf(a.x, b.x, acc);
    acc = fmaf(a.y, b.y, acc);
    acc = fmaf(a.z, b.z, acc);
    return fmaf(a.w, b.w, acc);
}

// bf16-rounded 8-element partial dot (two float4 pairs)
__device__ __forceinline__ float dot8bf(const float4* a, const float4* v, int li, float d) {
    #pragma unroll
    for (int h = 0; h < 2; ++h) {
        const float4 x = a[li * 2 + h], y = v[li * 2 + h];
        d = fmaf(bfm(x.x), bfm(y.x), d);
        d = fmaf(bfm(x.y), bfm(y.y), d);
        d = fmaf(bfm(x.z), bfm(y.z), d);
        d = fmaf(bfm(x.w), bfm(y.w), d);
    }
    return d;
}

// ---------------- embed: raw dots + norm^2 accumulation ----------------------
// grid (32 d-quads, 32 b-pairs) = 1024 blocks (4/CU; was 1/CU): one dim/wave.
__global__ __launch_bounds__(256) void embed_kernel(
    const float* __restrict__ fs, const float* __restrict__ ft,
    const float* __restrict__ Ws, const float* __restrict__ bs,
    const float* __restrict__ Wt, const float* __restrict__ bt,
    float* __restrict__ vraw_s, float* __restrict__ vraw_t,
    float* __restrict__ n2s, float* __restrict__ n2t)
{
    __shared__ __align__(16) float4 FS[512];    // 2 b x 1024 f
    __shared__ __align__(16) float4 FT[1024];   // 2 b x 2048 f

    const int t  = threadIdx.x;
    const int b0 = blockIdx.y * 2;

    for (int q = t; q < 512; q += 256) {
        const int b = q >> 8, i = q & 255;
        FS[q] = ((const float4*)(fs + (size_t)(b0 + b) * 1024))[i];
    }
    for (int q = t; q < 1024; q += 256) {
        const int b = q >> 9, i = q & 511;
        FT[q] = ((const float4*)(ft + (size_t)(b0 + b) * 2048))[i];
    }
    __syncthreads();

    const int w = t >> 6, lane = t & 63;
    const int d = blockIdx.x * 4 + w;          // one dim per wave

    {   // s-side
        const float4* wrow = (const float4*)(Ws + (size_t)d * 1024);
        float a0 = 0.0f, a1 = 0.0f;
        #pragma unroll
        for (int i = 0; i < 4; ++i) {
            const float4 wv = wrow[i * 64 + lane];
            a0 = dot4(wv, FS[i * 64 + lane], a0);
            a1 = dot4(wv, FS[256 + i * 64 + lane], a1);
        }
        a0 = wave_reduce64(a0) + bs[d];
        a1 = wave_reduce64(a1) + bs[d];
        if (lane == 0) {
            vraw_s[(size_t)b0 * 128 + d]       = a0;
            vraw_s[(size_t)(b0 + 1) * 128 + d] = a1;
            atomicAdd(&n2s[b0],     a0 * a0);
            atomicAdd(&n2s[b0 + 1], a1 * a1);
        }
    }
    {   // t-side
        const float4* wrow = (const float4*)(Wt + (size_t)d * 2048);
        float a0 = 0.0f, a1 = 0.0f;
        #pragma unroll
        for (int i = 0; i < 8; ++i) {
            const float4 wv = wrow[i * 64 + lane];
            a0 = dot4(wv, FT[i * 64 + lane], a0);
            a1 = dot4(wv, FT[512 + i * 64 + lane], a1);
        }
        a0 = wave_reduce64(a0) + bt[d];
        a1 = wave_reduce64(a1) + bt[d];
        if (lane == 0) {
            vraw_t[(size_t)b0 * 128 + d]       = a0;
            vraw_t[(size_t)(b0 + 1) * 128 + d] = a1;
            atomicAdd(&n2t[b0],     a0 * a0);
            atomicAdd(&n2t[b0 + 1], a1 * a1);
        }
    }
}

// ---------------- mask build: rowmask bitmap + duplicate overflow list -------
// For each negative (b,k): set bit b of rowmask[row]. atomicOr's return tells
// exactly one "first" per (b,row); every later occurrence appends to the
// overflow list (so bitmap + overflow reproduces exact multiplicities).
__global__ __launch_bounds__(256) void mask_kernel(
    const int* __restrict__ cidx,
    unsigned long long* __restrict__ rowmask,
    unsigned* __restrict__ ovfcnt, unsigned* __restrict__ ovf)
{
    const int b = blockIdx.x, part = blockIdx.y, t = threadIdx.x;
    __shared__ unsigned lcnt;
    __shared__ unsigned lbuf[OVF_CAP];
    if (t == 0) lcnt = 0;
    __syncthreads();

    const unsigned long long bit = 1ull << b;
    const int kbase = part * 1024 + 1;         // k in [1,16384], same as old gather
    #pragma unroll
    for (int j = 0; j < 4; ++j) {
        const int row = cidx[(size_t)b * KP1 + kbase + j * 256 + t];
        const unsigned long long old = atomicOr(&rowmask[row], bit);
        if (old & bit) {
            const unsigned p = atomicAdd(&lcnt, 1u);   // LDS atomic: cheap
            if (p < OVF_CAP) lbuf[p] = ((unsigned)b << 17) | (unsigned)row;
        }
    }
    __syncthreads();
    const int blk = b * 16 + part;
    const unsigned n = min(lcnt, (unsigned)OVF_CAP);
    if (t == 0) ovfcnt[blk] = n;
    for (unsigned q = t; q < n; q += 256) ovf[(size_t)blk * OVF_CAP + q] = lbuf[q];
}

// ---------------- fused bf16 MFMA GEMM + masked exp-sum (NO S array) ---------
// Same MFMA structure as round 2 (verified mapping: lane (m,q4) reg j holds
// S[row0+m][b = n*16+q4*4+j]). Instead of storing S (50 MB write + 50 MB
// gather re-read -- the 2 TB/s wall), consume each value in-register:
// if rowmask bit b of row set, accumulate exp(S*scale_b), exp^2. Only output:
// 2 atomicAdds per block into 8-sloted acc.
__global__ __launch_bounds__(256) void sgemm_kernel(
    const float* __restrict__ m1, const float* __restrict__ m2,
    const float* __restrict__ vraw_s, const float* __restrict__ vraw_t,
    const float* __restrict__ n2t, const float* __restrict__ n2s,
    const unsigned long long* __restrict__ rowmask,
    float* __restrict__ acc)
{
    const int t = threadIdx.x;
    const int bank = blockIdx.y;
    const float* __restrict__ bankp = bank ? m2 : m1;
    const float* __restrict__ vp    = bank ? vraw_s : vraw_t;
    const float* __restrict__ n2p   = bank ? n2s : n2t;

    const int lane = t & 63;
    const int m  = lane & 15;
    const int q4 = lane >> 4;

    // V fragments, register-resident
    short8 bfv[4][4];
    #pragma unroll
    for (int n = 0; n < 4; ++n) {
        const float4* vrow = (const float4*)(vp + (size_t)(n * 16 + m) * 128);
        #pragma unroll
        for (int kk = 0; kk < 4; ++kk) {
            const float4 lo = vrow[(kk * 4 + q4) * 2];
            const float4 hi = vrow[(kk * 4 + q4) * 2 + 1];
            bfv[n][kk] = pack_bf16(lo, hi);
        }
    }

    // per-lane scales for its 16 b's: scv[n][j] = INV_T*rsqrt(n2[n*16+q4*4+j])
    f32x4 scv[4];
    #pragma unroll
    for (int n = 0; n < 4; ++n) {
        const f32x4 nn = ((const f32x4*)n2p)[n * 4 + q4];
        #pragma unroll
        for (int j = 0; j < 4; ++j) scv[n][j] = INV_T * rsqrtf(nn[j]);
    }

    float se = 0.0f, se2 = 0.0f;

    const int wave   = (blockIdx.x << 2) | (t >> 6);
    const int nwaves = gridDim.x << 2;

    for (int cid = wave; cid < NCHUNKS; cid += nwaves) {
        const int row0 = cid << 4;
        const float4* arow = (const float4*)(bankp + (size_t)(row0 + m) * 128);

        float4 a[8];
        #pragma unroll
        for (int kk = 0; kk < 4; ++kk) {
            a[kk * 2]     = arow[(kk * 4 + q4) * 2];
            a[kk * 2 + 1] = arow[(kk * 4 + q4) * 2 + 1];
        }
        short8 af[4];
        #pragma unroll
        for (int kk = 0; kk < 4; ++kk)
            af[kk] = pack_bf16(a[kk * 2], a[kk * 2 + 1]);

        const unsigned long long msk = rowmask[row0 + m];

        #pragma unroll
        for (int n = 0; n < 4; ++n) {
            f32x4 av = {0.f, 0.f, 0.f, 0.f};
            #pragma unroll
            for (int kk = 0; kk < 4; ++kk)
                av = __builtin_amdgcn_mfma_f32_16x16x32_bf16(bfv[n][kk], af[kk], av, 0, 0, 0);
            const int base_b = n * 16 + q4 * 4;
            #pragma unroll
            for (int j = 0; j < 4; ++j) {
                const float mj = (float)((unsigned)((msk >> (base_b + j)) & 1ull));
                const float e = __expf(av[j] * scv[n][j]) * mj;
                se += e;
                se2 = fmaf(e, e, se2);
            }
        }
    }

    se  = wave_reduce64(se);
    se2 = wave_reduce64(se2);
    __shared__ float red[4][2];
    if (lane == 0) { red[t >> 6][0] = se; red[t >> 6][1] = se2; }
    __syncthreads();
    if (t < 2) {
        const float s = red[0][t] + red[1][t] + red[2][t] + red[3][t];
        atomicAdd(&acc[(blockIdx.x & 7) * 4 + bank * 2 + t], s);
    }
}

// ---------------- overflow duplicates: direct bf16-rounded dots --------------
// ~82K entries; each needs exp for BOTH banks. 16-lane group per entry.
__global__ __launch_bounds__(256) void ovf_kernel(
    const unsigned* __restrict__ ovfcnt, const unsigned* __restrict__ ovf,
    const float* __restrict__ m1, const float* __restrict__ m2,
    const float* __restrict__ vraw_t, const float* __restrict__ vraw_s,
    const float* __restrict__ n2t, const float* __restrict__ n2s,
    float* __restrict__ acc)
{
    const int blk = blockIdx.x, t = threadIdx.x;
    const int cnt = (int)ovfcnt[blk];
    const int wave = t >> 6, lane = t & 63, g = lane >> 4, li = lane & 15;

    float seT = 0.f, se2T = 0.f, seS = 0.f, se2S = 0.f;

    for (int i0 = 0; i0 * 16 < cnt; ++i0) {
        const int e = i0 * 16 + wave * 4 + g;
        const bool ok = e < cnt;
        const unsigned ue = ovf[(size_t)blk * OVF_CAP + (ok ? e : 0)];
        const int b = (int)(ue >> 17), row = (int)(ue & 0x1FFFFu);

        float dT = dot8bf((const float4*)(m1 + (size_t)row * 128),
                          (const float4*)(vraw_t + (size_t)b * 128), li, 0.f);
        float dS = dot8bf((const float4*)(m2 + (size_t)row * 128),
                          (const float4*)(vraw_s + (size_t)b * 128), li, 0.f);
        dT = group_reduce16(dT);
        dS = group_reduce16(dS);
        if (ok && li == 0) {
            const float eT = __expf(dT * INV_T * rsqrtf(n2t[b]));
            const float eS = __expf(dS * INV_T * rsqrtf(n2s[b]));
            seT += eT; se2T = fmaf(eT, eT, se2T);
            seS += eS; se2S = fmaf(eS, eS, se2S);
        }
    }

    seT = wave_reduce64(seT);  se2T = wave_reduce64(se2T);
    seS = wave_reduce64(seS);  se2S = wave_reduce64(se2S);
    __shared__ float red[4][4];
    if (lane == 0) {
        red[wave][0] = seT; red[wave][1] = se2T; red[wave][2] = seS; red[wave][3] = se2S;
    }
    __syncthreads();
    if (t < 4)
        atomicAdd(&acc[(blk & 7) * 4 + t], red[0][t] + red[1][t] + red[2][t] + red[3][t]);
}

// ---------------- final: positives (direct dots) + closed-form negatives -----
__global__ __launch_bounds__(256) void final_kernel(
    const int* __restrict__ idx,
    const float* __restrict__ m1, const float* __restrict__ m2,
    const float* __restrict__ vraw_t, const float* __restrict__ vraw_s,
    const float* __restrict__ n2t, const float* __restrict__ n2s,
    const float* __restrict__ acc, float* __restrict__ out)
{
    const int t = threadIdx.x, wave = t >> 6, lane = t & 63, g = lane >> 4, li = lane & 15;
    __shared__ float e1s[64], e2s[64];

    #pragma unroll
    for (int i = 0; i < 4; ++i) {
        const int b = wave * 16 + i * 4 + g;
        const int row = idx[b];
        float dT = dot8bf((const float4*)(m1 + (size_t)row * 128),
                          (const float4*)(vraw_t + (size_t)b * 128), li, 0.f);
        float dS = dot8bf((const float4*)(m2 + (size_t)row * 128),
                          (const float4*)(vraw_s + (size_t)b * 128), li, 0.f);
        dT = group_reduce16(dT);
        dS = group_reduce16(dS);
        if (li == 0) {
            e1s[b] = __expf(dT * INV_T * rsqrtf(n2t[b]));
            e2s[b] = __expf(dS * INV_T * rsqrtf(n2s[b]));
        }
    }
    __syncthreads();

    if (t < 64) {
        const int b = t;
        const float c = 0.16384f + 1e-7f;
        const float e1p = e1s[b], e2p = e2s[b];

        const float pseT = wave_reduce64(e1p);
        const float pseS = wave_reduce64(e2p);

        float seT_neg = 0.f, se2T_neg = 0.f, seS_neg = 0.f, se2S_neg = 0.f;
        #pragma unroll
        for (int s = 0; s < 8; ++s) {
            seT_neg  += acc[s * 4 + 0];
            se2T_neg += acc[s * 4 + 1];
            seS_neg  += acc[s * 4 + 2];
            se2S_neg += acc[s * 4 + 3];
        }

        const float zn = (float)PTOT / (float)NDATA;
        const float invZt = zn / (seT_neg + pseT);   // Z-sum includes positives
        const float invZs = zn / (seS_neg + pseS);

        const float PB = (float)(PTOT - BSZ);        // 1,048,576
        const float LOG_MPN_C = -6.1035156e-7f;      // ln(mPn / (mPn + 1e-7))
        const float ic = 1.0f / c;

        const float negT = PB * LOG_MPN_C
                         - seT_neg * invZt * ic
                         + 0.5f * se2T_neg * invZt * invZt * ic * ic;
        const float negS = PB * LOG_MPN_C
                         - seS_neg * invZs * ic
                         + 0.5f * se2S_neg * invZs * invZs * ic * ic;

        const float x0t = e1p * invZt, x0s = e2p * invZs;
        float pos = __logf(x0t / (x0t + c)) + __logf(x0s / (x0s + c));
        pos = wave_reduce64(pos);

        if (b == 0) out[0] = -(negT + negS + pos) * (1.0f / 64.0f);
    }
}

extern "C" void kernel_launch(void* const* d_in, const int* in_sizes, int n_in,
                              void* d_out, int out_size, void* d_ws, size_t ws_size,
                              hipStream_t stream) {
    const float* fs   = (const float*)d_in[0];
    const float* ft   = (const float*)d_in[1];
    const int*   idx  = (const int*)d_in[2];
    const int*   cidx = (const int*)d_in[3];
    const float* Ws   = (const float*)d_in[4];
    const float* bs   = (const float*)d_in[5];
    const float* Wt   = (const float*)d_in[6];
    const float* bt   = (const float*)d_in[7];
    const float* m1   = (const float*)d_in[8];
    const float* m2   = (const float*)d_in[9];
    float* out = (float*)d_out;

    // ws layout (floats):
    //   [0..64)      n2t
    //   [64..128)    n2s
    //   [128..160)   acc (8 slots x 4)
    //   [160..256)   pad
    //   [256..200256)        rowmask (100000 x u64)
    //   [200256..201280)     ovfcnt (1024 x u32)
    //   [201280..463424)     ovf (1024 x 256 x u32)
    float* ws     = (float*)d_ws;
    float* n2t    = ws;
    float* n2s    = ws + 64;
    float* acc    = ws + 128;
    unsigned long long* rowmask = (unsigned long long*)(ws + 256);
    unsigned* ovfcnt = (unsigned*)(ws + 200256);
    unsigned* ovf    = (unsigned*)(ws + 201280);
    float* vraw_s = ws + 201280 + (size_t)NMBLK * OVF_CAP;   // 8192
    float* vraw_t = vraw_s + 8192;                            // 8192

    // zero n2t, n2s, acc, pad, rowmask, ovfcnt in one shot (805,120 B)
    hipMemsetAsync(ws, 0, (size_t)(256 + 200000 + 1024) * sizeof(float), stream);

    embed_kernel<<<dim3(32, 32), dim3(256), 0, stream>>>(
        fs, ft, Ws, bs, Wt, bt, vraw_s, vraw_t, n2s, n2t);
    mask_kernel<<<dim3(64, 16), dim3(256), 0, stream>>>(
        cidx, rowmask, ovfcnt, ovf);
    sgemm_kernel<<<dim3(512, 2), dim3(256), 0, stream>>>(
        m1, m2, vraw_s, vraw_t, n2t, n2s, rowmask, acc);
    ovf_kernel<<<dim3(NMBLK), dim3(256), 0, stream>>>(
        ovfcnt, ovf, m1, m2, vraw_t, vraw_s, n2t, n2s, acc);
    final_kernel<<<dim3(1), dim3(256), 0, stream>>>(
        idx, m1, m2, vraw_t, vraw_s, n2t, n2s, acc, out);
}

// Round 4
// 230.397 us; speedup vs baseline: 1.2946x; 1.2946x over previous
//
#include <hip/hip_runtime.h>

#define NDATA 100000
#define KP1 16385            // NCE_K + 1
#define BSZ 64
#define PTOT (BSZ * KP1)     // 1,048,640
#define NCHUNKS 6250         // NDATA / 16 (exact)
#define INV_T (1.0f / 0.07f)
#define OVF_CAP 256          // per-maskbuild-block dup capacity (expect ~80, 20 sigma)
#define NMBLK 1024           // maskbuild blocks = 64 b x 16 parts
#define ACC_STRIDE 64        // floats; one 256-B cache line per acc group
#define ACC_GROUPS 32

typedef short short8 __attribute__((ext_vector_type(8)));
typedef float f32x4 __attribute__((ext_vector_type(4)));

__device__ __forceinline__ float wave_reduce64(float v) {
    #pragma unroll
    for (int off = 32; off >= 1; off >>= 1) v += __shfl_xor(v, off);
    return v;
}

__device__ __forceinline__ float group_reduce16(float v) {
    v += __shfl_xor(v, 8); v += __shfl_xor(v, 4);
    v += __shfl_xor(v, 2); v += __shfl_xor(v, 1);
    return v;
}

__device__ __forceinline__ unsigned short f2bf(float f) {
    unsigned u = __float_as_uint(f);
    u += 0x7FFFu + ((u >> 16) & 1u);   // round-to-nearest-even
    return (unsigned short)(u >> 16);
}

// bf16-round a float and return it as float (matches MFMA input rounding)
__device__ __forceinline__ float bfm(float x) {
    return __uint_as_float(((unsigned)f2bf(x)) << 16);
}

__device__ __forceinline__ short8 pack_bf16(float4 lo, float4 hi) {
    short8 r;
    r[0] = (short)f2bf(lo.x); r[1] = (short)f2bf(lo.y);
    r[2] = (short)f2bf(lo.z); r[3] = (short)f2bf(lo.w);
    r[4] = (short)f2bf(hi.x); r[5] = (short)f2bf(hi.y);
    r[6] = (short)f2bf(hi.z); r[7] = (short)f2bf(hi.w);
    return r;
}

__device__ __forceinline__ float dot4(float4 a, float4 b, float acc) {
    acc = fmaf(a.x, b.x, acc);
    acc = fmaf(a.y, b.y, acc);
    acc = fmaf(a.z, b.z, acc);
    return fmaf(a.w, b.w, acc);
}

// bf16-rounded 8-element partial dot (two float4 pairs)
__device__ __forceinline__ float dot8bf(const float4* a, const float4* v, int li, float d) {
    #pragma unroll
    for (int h = 0; h < 2; ++h) {
        const float4 x = a[li * 2 + h], y = v[li * 2 + h];
        d = fmaf(bfm(x.x), bfm(y.x), d);
        d = fmaf(bfm(x.y), bfm(y.y), d);
        d = fmaf(bfm(x.z), bfm(y.z), d);
        d = fmaf(bfm(x.w), bfm(y.w), d);
    }
    return d;
}

// ---------------- embed: raw dots only (NO atomics) --------------------------
// grid (32 d-quads, 32 b-pairs) = 1024 blocks, one dim/wave. R3's 80 us came
// from 16K same-line atomics into n2s/n2t (2 cache lines); n^2 moved to
// norm_kernel.
__global__ __launch_bounds__(256) void embed_kernel(
    const float* __restrict__ fs, const float* __restrict__ ft,
    const float* __restrict__ Ws, const float* __restrict__ bs,
    const float* __restrict__ Wt, const float* __restrict__ bt,
    float* __restrict__ vraw_s, float* __restrict__ vraw_t)
{
    __shared__ __align__(16) float4 FS[512];    // 2 b x 1024 f
    __shared__ __align__(16) float4 FT[1024];   // 2 b x 2048 f

    const int t  = threadIdx.x;
    const int b0 = blockIdx.y * 2;

    for (int q = t; q < 512; q += 256) {
        const int b = q >> 8, i = q & 255;
        FS[q] = ((const float4*)(fs + (size_t)(b0 + b) * 1024))[i];
    }
    for (int q = t; q < 1024; q += 256) {
        const int b = q >> 9, i = q & 511;
        FT[q] = ((const float4*)(ft + (size_t)(b0 + b) * 2048))[i];
    }
    __syncthreads();

    const int w = t >> 6, lane = t & 63;
    const int d = blockIdx.x * 4 + w;          // one dim per wave

    {   // s-side
        const float4* wrow = (const float4*)(Ws + (size_t)d * 1024);
        float a0 = 0.0f, a1 = 0.0f;
        #pragma unroll
        for (int i = 0; i < 4; ++i) {
            const float4 wv = wrow[i * 64 + lane];
            a0 = dot4(wv, FS[i * 64 + lane], a0);
            a1 = dot4(wv, FS[256 + i * 64 + lane], a1);
        }
        a0 = wave_reduce64(a0) + bs[d];
        a1 = wave_reduce64(a1) + bs[d];
        if (lane == 0) {
            vraw_s[(size_t)b0 * 128 + d]       = a0;
            vraw_s[(size_t)(b0 + 1) * 128 + d] = a1;
        }
    }
    {   // t-side
        const float4* wrow = (const float4*)(Wt + (size_t)d * 2048);
        float a0 = 0.0f, a1 = 0.0f;
        #pragma unroll
        for (int i = 0; i < 8; ++i) {
            const float4 wv = wrow[i * 64 + lane];
            a0 = dot4(wv, FT[i * 64 + lane], a0);
            a1 = dot4(wv, FT[512 + i * 64 + lane], a1);
        }
        a0 = wave_reduce64(a0) + bt[d];
        a1 = wave_reduce64(a1) + bt[d];
        if (lane == 0) {
            vraw_t[(size_t)b0 * 128 + d]       = a0;
            vraw_t[(size_t)(b0 + 1) * 128 + d] = a1;
        }
    }
}

// ---------------- norm: scale[b] = INV_T * rsqrt(sum_d v[b][d]^2) ------------
// grid(2): block 0 -> (vraw_t -> sct), block 1 -> (vraw_s -> scs). 64 KB L2-hot.
__global__ __launch_bounds__(256) void norm_kernel(
    const float* __restrict__ vraw_t, const float* __restrict__ vraw_s,
    float* __restrict__ sct, float* __restrict__ scs)
{
    const float* __restrict__ v = blockIdx.x ? vraw_s : vraw_t;
    float* __restrict__ sc      = blockIdx.x ? scs : sct;
    const int t = threadIdx.x, b = t >> 2, g = t & 3;   // 4 lanes per b
    const float4* row = (const float4*)(v + (size_t)b * 128 + g * 32);
    float s = 0.0f;
    #pragma unroll
    for (int j = 0; j < 8; ++j) s = dot4(row[j], row[j], s);
    s += __shfl_xor(s, 1);
    s += __shfl_xor(s, 2);
    if (g == 0) sc[b] = INV_T * rsqrtf(s);
}

// ---------------- mask build: rowmask bitmap + duplicate overflow list -------
__global__ __launch_bounds__(256) void mask_kernel(
    const int* __restrict__ cidx,
    unsigned long long* __restrict__ rowmask,
    unsigned* __restrict__ ovfcnt, unsigned* __restrict__ ovf)
{
    const int b = blockIdx.x, part = blockIdx.y, t = threadIdx.x;
    __shared__ unsigned lcnt;
    __shared__ unsigned lbuf[OVF_CAP];
    if (t == 0) lcnt = 0;
    __syncthreads();

    const unsigned long long bit = 1ull << b;
    const int kbase = part * 1024 + 1;         // k in [1,16384]
    #pragma unroll
    for (int j = 0; j < 4; ++j) {
        const int row = cidx[(size_t)b * KP1 + kbase + j * 256 + t];
        const unsigned long long old = atomicOr(&rowmask[row], bit);
        if (old & bit) {
            const unsigned p = atomicAdd(&lcnt, 1u);   // LDS atomic: cheap
            if (p < OVF_CAP) lbuf[p] = ((unsigned)b << 17) | (unsigned)row;
        }
    }
    __syncthreads();
    const int blk = b * 16 + part;
    const unsigned n = min(lcnt, (unsigned)OVF_CAP);
    if (t == 0) ovfcnt[blk] = n;
    for (unsigned q = t; q < n; q += 256) ovf[(size_t)blk * OVF_CAP + q] = lbuf[q];
}

// ---------------- fused bf16 MFMA GEMM + masked exp-sum (NO S array) ---------
// lane (m,q4) reg j of the (swapped) D-frag = S[row0+m][b = n*16+q4*4+j]
// (mapping verified by R2/R3 passes). acc atomics: one cache line per
// blockIdx.x&31 group (R3 put 2048 atomics on ONE line).
__global__ __launch_bounds__(256) void sgemm_kernel(
    const float* __restrict__ m1, const float* __restrict__ m2,
    const float* __restrict__ vraw_s, const float* __restrict__ vraw_t,
    const float* __restrict__ sct, const float* __restrict__ scs,
    const unsigned long long* __restrict__ rowmask,
    float* __restrict__ acc)
{
    const int t = threadIdx.x;
    const int bank = blockIdx.y;
    const float* __restrict__ bankp = bank ? m2 : m1;
    const float* __restrict__ vp    = bank ? vraw_s : vraw_t;
    const float* __restrict__ scp   = bank ? scs : sct;

    const int lane = t & 63;
    const int m  = lane & 15;
    const int q4 = lane >> 4;

    // V fragments, register-resident
    short8 bfv[4][4];
    #pragma unroll
    for (int n = 0; n < 4; ++n) {
        const float4* vrow = (const float4*)(vp + (size_t)(n * 16 + m) * 128);
        #pragma unroll
        for (int kk = 0; kk < 4; ++kk) {
            const float4 lo = vrow[(kk * 4 + q4) * 2];
            const float4 hi = vrow[(kk * 4 + q4) * 2 + 1];
            bfv[n][kk] = pack_bf16(lo, hi);
        }
    }

    // per-lane scales for its 16 b's
    f32x4 scv[4];
    #pragma unroll
    for (int n = 0; n < 4; ++n) scv[n] = ((const f32x4*)scp)[n * 4 + q4];

    float se = 0.0f, se2 = 0.0f;

    const int wave   = (blockIdx.x << 2) | (t >> 6);
    const int nwaves = gridDim.x << 2;

    for (int cid = wave; cid < NCHUNKS; cid += nwaves) {
        const int row0 = cid << 4;
        const float4* arow = (const float4*)(bankp + (size_t)(row0 + m) * 128);

        float4 a[8];
        #pragma unroll
        for (int kk = 0; kk < 4; ++kk) {
            a[kk * 2]     = arow[(kk * 4 + q4) * 2];
            a[kk * 2 + 1] = arow[(kk * 4 + q4) * 2 + 1];
        }
        short8 af[4];
        #pragma unroll
        for (int kk = 0; kk < 4; ++kk)
            af[kk] = pack_bf16(a[kk * 2], a[kk * 2 + 1]);

        const unsigned long long msk = rowmask[row0 + m];

        #pragma unroll
        for (int n = 0; n < 4; ++n) {
            f32x4 av = {0.f, 0.f, 0.f, 0.f};
            #pragma unroll
            for (int kk = 0; kk < 4; ++kk)
                av = __builtin_amdgcn_mfma_f32_16x16x32_bf16(bfv[n][kk], af[kk], av, 0, 0, 0);
            const int base_b = n * 16 + q4 * 4;
            #pragma unroll
            for (int j = 0; j < 4; ++j) {
                const float mj = (float)((unsigned)((msk >> (base_b + j)) & 1ull));
                const float e = __expf(av[j] * scv[n][j]) * mj;
                se += e;
                se2 = fmaf(e, e, se2);
            }
        }
    }

    se  = wave_reduce64(se);
    se2 = wave_reduce64(se2);
    __shared__ float red[4][2];
    if (lane == 0) { red[t >> 6][0] = se; red[t >> 6][1] = se2; }
    __syncthreads();
    if (t < 2) {
        const float s = red[0][t] + red[1][t] + red[2][t] + red[3][t];
        atomicAdd(&acc[(blockIdx.x & (ACC_GROUPS - 1)) * ACC_STRIDE + bank * 2 + t], s);
    }
}

// ---------------- overflow duplicates: direct bf16-rounded dots --------------
__global__ __launch_bounds__(256) void ovf_kernel(
    const unsigned* __restrict__ ovfcnt, const unsigned* __restrict__ ovf,
    const float* __restrict__ m1, const float* __restrict__ m2,
    const float* __restrict__ vraw_t, const float* __restrict__ vraw_s,
    const float* __restrict__ sct, const float* __restrict__ scs,
    float* __restrict__ acc)
{
    const int blk = blockIdx.x, t = threadIdx.x;
    const int cnt = (int)ovfcnt[blk];
    const int wave = t >> 6, lane = t & 63, g = lane >> 4, li = lane & 15;

    float seT = 0.f, se2T = 0.f, seS = 0.f, se2S = 0.f;

    for (int i0 = 0; i0 * 16 < cnt; ++i0) {
        const int e = i0 * 16 + wave * 4 + g;
        const bool ok = e < cnt;
        const unsigned ue = ovf[(size_t)blk * OVF_CAP + (ok ? e : 0)];
        const int b = (int)(ue >> 17), row = (int)(ue & 0x1FFFFu);

        float dT = dot8bf((const float4*)(m1 + (size_t)row * 128),
                          (const float4*)(vraw_t + (size_t)b * 128), li, 0.f);
        float dS = dot8bf((const float4*)(m2 + (size_t)row * 128),
                          (const float4*)(vraw_s + (size_t)b * 128), li, 0.f);
        dT = group_reduce16(dT);
        dS = group_reduce16(dS);
        if (ok && li == 0) {
            const float eT = __expf(dT * sct[b]);
            const float eS = __expf(dS * scs[b]);
            seT += eT; se2T = fmaf(eT, eT, se2T);
            seS += eS; se2S = fmaf(eS, eS, se2S);
        }
    }

    seT = wave_reduce64(seT);  se2T = wave_reduce64(se2T);
    seS = wave_reduce64(seS);  se2S = wave_reduce64(se2S);
    __shared__ float red[4][4];
    if (lane == 0) {
        red[wave][0] = seT; red[wave][1] = se2T; red[wave][2] = seS; red[wave][3] = se2S;
    }
    __syncthreads();
    if (t < 4)
        atomicAdd(&acc[(blk & (ACC_GROUPS - 1)) * ACC_STRIDE + t],
                  red[0][t] + red[1][t] + red[2][t] + red[3][t]);
}

// ---------------- final: positives (direct dots) + closed-form negatives -----
__global__ __launch_bounds__(256) void final_kernel(
    const int* __restrict__ idx,
    const float* __restrict__ m1, const float* __restrict__ m2,
    const float* __restrict__ vraw_t, const float* __restrict__ vraw_s,
    const float* __restrict__ sct, const float* __restrict__ scs,
    const float* __restrict__ acc, float* __restrict__ out)
{
    const int t = threadIdx.x, wave = t >> 6, lane = t & 63, g = lane >> 4, li = lane & 15;
    __shared__ float e1s[64], e2s[64];

    #pragma unroll
    for (int i = 0; i < 4; ++i) {
        const int b = wave * 16 + i * 4 + g;
        const int row = idx[b];
        float dT = dot8bf((const float4*)(m1 + (size_t)row * 128),
                          (const float4*)(vraw_t + (size_t)b * 128), li, 0.f);
        float dS = dot8bf((const float4*)(m2 + (size_t)row * 128),
                          (const float4*)(vraw_s + (size_t)b * 128), li, 0.f);
        dT = group_reduce16(dT);
        dS = group_reduce16(dS);
        if (li == 0) {
            e1s[b] = __expf(dT * sct[b]);
            e2s[b] = __expf(dS * scs[b]);
        }
    }
    __syncthreads();

    if (t < 64) {
        const int b = t;
        const float c = 0.16384f + 1e-7f;
        const float e1p = e1s[b], e2p = e2s[b];

        const float pseT = wave_reduce64(e1p);
        const float pseS = wave_reduce64(e2p);

        float seT_neg = 0.f, se2T_neg = 0.f, seS_neg = 0.f, se2S_neg = 0.f;
        for (int s = 0; s < ACC_GROUPS; ++s) {
            seT_neg  += acc[s * ACC_STRIDE + 0];
            se2T_neg += acc[s * ACC_STRIDE + 1];
            seS_neg  += acc[s * ACC_STRIDE + 2];
            se2S_neg += acc[s * ACC_STRIDE + 3];
        }

        const float zn = (float)PTOT / (float)NDATA;
        const float invZt = zn / (seT_neg + pseT);   // Z-sum includes positives
        const float invZs = zn / (seS_neg + pseS);

        const float PB = (float)(PTOT - BSZ);        // 1,048,576
        const float LOG_MPN_C = -6.1035156e-7f;      // ln(mPn / (mPn + 1e-7))
        const float ic = 1.0f / c;

        const float negT = PB * LOG_MPN_C
                         - seT_neg * invZt * ic
                         + 0.5f * se2T_neg * invZt * invZt * ic * ic;
        const float negS = PB * LOG_MPN_C
                         - seS_neg * invZs * ic
                         + 0.5f * se2S_neg * invZs * invZs * ic * ic;

        const float x0t = e1p * invZt, x0s = e2p * invZs;
        float pos = __logf(x0t / (x0t + c)) + __logf(x0s / (x0s + c));
        pos = wave_reduce64(pos);

        if (b == 0) out[0] = -(negT + negS + pos) * (1.0f / 64.0f);
    }
}

extern "C" void kernel_launch(void* const* d_in, const int* in_sizes, int n_in,
                              void* d_out, int out_size, void* d_ws, size_t ws_size,
                              hipStream_t stream) {
    const float* fs   = (const float*)d_in[0];
    const float* ft   = (const float*)d_in[1];
    const int*   idx  = (const int*)d_in[2];
    const int*   cidx = (const int*)d_in[3];
    const float* Ws   = (const float*)d_in[4];
    const float* bs   = (const float*)d_in[5];
    const float* Wt   = (const float*)d_in[6];
    const float* bt   = (const float*)d_in[7];
    const float* m1   = (const float*)d_in[8];
    const float* m2   = (const float*)d_in[9];
    float* out = (float*)d_out;

    // ws layout (float index):
    //   [0..64)          sct
    //   [64..128)        scs
    //   [128..2176)      acc (32 groups x 64-float line; 4 used per group)
    //   [2176..4096)     pad
    //   [4096..204096)   rowmask (100000 x u64)
    //   [204096..205120) ovfcnt (1024 x u32)
    //   [205120..467264) ovf (1024 x 256 x u32)
    //   [467264..475456) vraw_s
    //   [475456..483648) vraw_t
    float* ws     = (float*)d_ws;
    float* sct    = ws;
    float* scs    = ws + 64;
    float* acc    = ws + 128;
    unsigned long long* rowmask = (unsigned long long*)(ws + 4096);
    unsigned* ovfcnt = (unsigned*)(ws + 204096);
    unsigned* ovf    = (unsigned*)(ws + 205120);
    float* vraw_s = ws + 467264;
    float* vraw_t = ws + 475456;

    // zero acc + rowmask + ovfcnt (sct/scs/vraw are fully overwritten)
    hipMemsetAsync(ws + 128, 0, (size_t)(205120 - 128) * sizeof(float), stream);

    embed_kernel<<<dim3(32, 32), dim3(256), 0, stream>>>(
        fs, ft, Ws, bs, Wt, bt, vraw_s, vraw_t);
    norm_kernel<<<dim3(2), dim3(256), 0, stream>>>(
        vraw_t, vraw_s, sct, scs);
    mask_kernel<<<dim3(64, 16), dim3(256), 0, stream>>>(
        cidx, rowmask, ovfcnt, ovf);
    sgemm_kernel<<<dim3(521, 2), dim3(256), 0, stream>>>(
        m1, m2, vraw_s, vraw_t, sct, scs, rowmask, acc);
    ovf_kernel<<<dim3(NMBLK), dim3(256), 0, stream>>>(
        ovfcnt, ovf, m1, m2, vraw_t, vraw_s, sct, scs, acc);
    final_kernel<<<dim3(1), dim3(256), 0, stream>>>(
        idx, m1, m2, vraw_t, vraw_s, sct, scs, acc, out);
}

// Round 6
// 212.329 us; speedup vs baseline: 1.4047x; 1.0851x over previous
//
#include <hip/hip_runtime.h>

#define NDATA 100000
#define KP1 16385            // NCE_K + 1
#define BSZ 64
#define PTOT (BSZ * KP1)     // 1,048,640
#define NCHUNKS 6250         // NDATA / 16 (exact)
#define INV_T (1.0f / 0.07f)
#define ACC_STRIDE 64        // floats; one 256-B cache line per acc group
#define ACC_GROUPS 32
#define SG_NWAVES 1024       // sgemm: 256 blocks x 4 waves per bank (grid fixed!)
#define SG_NITER 7           // ceil(NCHUNKS / SG_NWAVES)

typedef short short8 __attribute__((ext_vector_type(8)));
typedef float f32x4 __attribute__((ext_vector_type(4)));

__device__ __forceinline__ float wave_reduce64(float v) {
    #pragma unroll
    for (int off = 32; off >= 1; off >>= 1) v += __shfl_xor(v, off);
    return v;
}

__device__ __forceinline__ float group_reduce16(float v) {
    v += __shfl_xor(v, 8); v += __shfl_xor(v, 4);
    v += __shfl_xor(v, 2); v += __shfl_xor(v, 1);
    return v;
}

__device__ __forceinline__ unsigned short f2bf(float f) {
    unsigned u = __float_as_uint(f);
    u += 0x7FFFu + ((u >> 16) & 1u);   // round-to-nearest-even
    return (unsigned short)(u >> 16);
}

// bf16-round a float and return it as float (matches MFMA input rounding)
__device__ __forceinline__ float bfm(float x) {
    return __uint_as_float(((unsigned)f2bf(x)) << 16);
}

__device__ __forceinline__ short8 pack_bf16(float4 lo, float4 hi) {
    short8 r;
    r[0] = (short)f2bf(lo.x); r[1] = (short)f2bf(lo.y);
    r[2] = (short)f2bf(lo.z); r[3] = (short)f2bf(lo.w);
    r[4] = (short)f2bf(hi.x); r[5] = (short)f2bf(hi.y);
    r[6] = (short)f2bf(hi.z); r[7] = (short)f2bf(hi.w);
    return r;
}

__device__ __forceinline__ float dot4(float4 a, float4 b, float acc) {
    acc = fmaf(a.x, b.x, acc);
    acc = fmaf(a.y, b.y, acc);
    acc = fmaf(a.z, b.z, acc);
    return fmaf(a.w, b.w, acc);
}

// bf16-rounded 8-element partial dot (two float4 pairs)
__device__ __forceinline__ float dot8bf(const float4* a, const float4* v, int li, float d) {
    #pragma unroll
    for (int h = 0; h < 2; ++h) {
        const float4 x = a[li * 2 + h], y = v[li * 2 + h];
        d = fmaf(bfm(x.x), bfm(y.x), d);
        d = fmaf(bfm(x.y), bfm(y.y), d);
        d = fmaf(bfm(x.z), bfm(y.z), d);
        d = fmaf(bfm(x.w), bfm(y.w), d);
    }
    return d;
}

// ---------------- embed: raw dots only (no atomics) --------------------------
__global__ __launch_bounds__(256) void embed_kernel(
    const float* __restrict__ fs, const float* __restrict__ ft,
    const float* __restrict__ Ws, const float* __restrict__ bs,
    const float* __restrict__ Wt, const float* __restrict__ bt,
    float* __restrict__ vraw_s, float* __restrict__ vraw_t)
{
    __shared__ __align__(16) float4 FS[512];    // 2 b x 1024 f
    __shared__ __align__(16) float4 FT[1024];   // 2 b x 2048 f

    const int t  = threadIdx.x;
    const int b0 = blockIdx.y * 2;

    for (int q = t; q < 512; q += 256) {
        const int b = q >> 8, i = q & 255;
        FS[q] = ((const float4*)(fs + (size_t)(b0 + b) * 1024))[i];
    }
    for (int q = t; q < 1024; q += 256) {
        const int b = q >> 9, i = q & 511;
        FT[q] = ((const float4*)(ft + (size_t)(b0 + b) * 2048))[i];
    }
    __syncthreads();

    const int w = t >> 6, lane = t & 63;
    const int d = blockIdx.x * 4 + w;          // one dim per wave

    {   // s-side
        const float4* wrow = (const float4*)(Ws + (size_t)d * 1024);
        float a0 = 0.0f, a1 = 0.0f;
        #pragma unroll
        for (int i = 0; i < 4; ++i) {
            const float4 wv = wrow[i * 64 + lane];
            a0 = dot4(wv, FS[i * 64 + lane], a0);
            a1 = dot4(wv, FS[256 + i * 64 + lane], a1);
        }
        a0 = wave_reduce64(a0) + bs[d];
        a1 = wave_reduce64(a1) + bs[d];
        if (lane == 0) {
            vraw_s[(size_t)b0 * 128 + d]       = a0;
            vraw_s[(size_t)(b0 + 1) * 128 + d] = a1;
        }
    }
    {   // t-side
        const float4* wrow = (const float4*)(Wt + (size_t)d * 2048);
        float a0 = 0.0f, a1 = 0.0f;
        #pragma unroll
        for (int i = 0; i < 8; ++i) {
            const float4 wv = wrow[i * 64 + lane];
            a0 = dot4(wv, FT[i * 64 + lane], a0);
            a1 = dot4(wv, FT[512 + i * 64 + lane], a1);
        }
        a0 = wave_reduce64(a0) + bt[d];
        a1 = wave_reduce64(a1) + bt[d];
        if (lane == 0) {
            vraw_t[(size_t)b0 * 128 + d]       = a0;
            vraw_t[(size_t)(b0 + 1) * 128 + d] = a1;
        }
    }
}

// ---------------- norm: scale[b] = INV_T * rsqrt(sum_d v[b][d]^2) ------------
__global__ __launch_bounds__(256) void norm_kernel(
    const float* __restrict__ vraw_t, const float* __restrict__ vraw_s,
    float* __restrict__ sct, float* __restrict__ scs)
{
    const float* __restrict__ v = blockIdx.x ? vraw_s : vraw_t;
    float* __restrict__ sc      = blockIdx.x ? scs : sct;
    const int t = threadIdx.x, b = t >> 2, g = t & 3;   // 4 lanes per b
    const float4* row = (const float4*)(v + (size_t)b * 128 + g * 32);
    float s = 0.0f;
    #pragma unroll
    for (int j = 0; j < 8; ++j) s = dot4(row[j], row[j], s);
    s += __shfl_xor(s, 1);
    s += __shfl_xor(s, 2);
    if (g == 0) sc[b] = INV_T * rsqrtf(s);
}

// ---------------- histogram: cnt[row][b] (uint8, packed 4/word) --------------
// Exact multiplicity of (b,row) over negatives k=1..16384. Replaces R4's
// bitmap + overflow list (ovf_kernel re-read ~84 MB of scattered bank rows;
// gone). Max mult per pair is ~O(5) (16384 draws over 100K rows) << 255.
__global__ __launch_bounds__(256) void hist_kernel(
    const int* __restrict__ cidx, unsigned* __restrict__ cnt)
{
    const int b = blockIdx.x, part = blockIdx.y, t = threadIdx.x;
    const unsigned inc = 1u << ((b & 3) * 8);
    const int w = b >> 2;
    const int kbase = part * 1024 + 1;         // k in [1,16384]
    #pragma unroll
    for (int j = 0; j < 4; ++j) {
        const int row = cidx[(size_t)b * KP1 + kbase + j * 256 + t];
        atomicAdd(&cnt[(size_t)row * 16 + w], inc);
    }
}

// ---------------- fused bf16 MFMA GEMM + weighted exp-sum (no S array) -------
// lane (m,q4) reg j of the (swapped) D-frag = S[row0+m][b = n*16+q4*4+j]
// (mapping verified R2-R4). Explicit 2-buffer register pipeline: chunk i+1's
// 12 loads (8x16B bank + 4x4B cnt) are issued BEFORE chunk i is consumed, so
// the wave never sits with 0 loads in flight (R4: VGPR=84 proved the compiler
// does NOT prefetch; every iteration paid a full vmcnt(0) drain bubble).
// Validity handled by a scalar mask applied at USE time (cnt=0 => no
// contribution), so tail chunks need no branches and no early waitcnt.
#define SG_ISSUE(AB, CB, VM, CID)                                            \
  {                                                                          \
    const int cc_ = ((CID) < NCHUNKS) ? (CID) : (NCHUNKS - 1);               \
    VM = ((CID) < NCHUNKS) ? ~0u : 0u;                                       \
    const int r0_ = cc_ << 4;                                                \
    const float4* ar_ = (const float4*)(bankp + (size_t)(r0_ + m) * 128);    \
    _Pragma("unroll")                                                        \
    for (int kk = 0; kk < 4; ++kk) {                                         \
      AB[kk * 2]     = ar_[(kk * 4 + q4) * 2];                               \
      AB[kk * 2 + 1] = ar_[(kk * 4 + q4) * 2 + 1];                           \
    }                                                                        \
    _Pragma("unroll")                                                        \
    for (int n = 0; n < 4; ++n)                                              \
      CB[n] = cnt[(size_t)(r0_ + m) * 16 + n * 4 + q4];                      \
  }

#define SG_PROCESS(AB, CB, VM)                                               \
  {                                                                          \
    short8 af_[4];                                                           \
    _Pragma("unroll")                                                        \
    for (int kk = 0; kk < 4; ++kk)                                           \
      af_[kk] = pack_bf16(AB[kk * 2], AB[kk * 2 + 1]);                       \
    _Pragma("unroll")                                                        \
    for (int n = 0; n < 4; ++n) {                                            \
      f32x4 av = {0.f, 0.f, 0.f, 0.f};                                       \
      _Pragma("unroll")                                                      \
      for (int kk = 0; kk < 4; ++kk)                                         \
        av = __builtin_amdgcn_mfma_f32_16x16x32_bf16(bfv[n][kk], af_[kk], av, 0, 0, 0); \
      const unsigned cw_ = CB[n] & VM;                                       \
      _Pragma("unroll")                                                      \
      for (int j = 0; j < 4; ++j) {                                          \
        const float fm_ = (float)((cw_ >> (8 * j)) & 255u);                  \
        const float e_  = __expf(av[j] * scv[n][j]);                         \
        se  = fmaf(e_, fm_, se);                                             \
        se2 = fmaf(e_ * fm_, e_, se2);                                       \
      }                                                                      \
    }                                                                        \
  }

__global__ __launch_bounds__(256) void sgemm_kernel(
    const float* __restrict__ m1, const float* __restrict__ m2,
    const float* __restrict__ vraw_s, const float* __restrict__ vraw_t,
    const float* __restrict__ sct, const float* __restrict__ scs,
    const unsigned* __restrict__ cnt,
    float* __restrict__ acc)
{
    const int t = threadIdx.x;
    const int bank = blockIdx.y;
    const float* __restrict__ bankp = bank ? m2 : m1;
    const float* __restrict__ vp    = bank ? vraw_s : vraw_t;
    const float* __restrict__ scp   = bank ? scs : sct;

    const int lane = t & 63;
    const int m  = lane & 15;
    const int q4 = lane >> 4;

    // V fragments, register-resident
    short8 bfv[4][4];
    #pragma unroll
    for (int n = 0; n < 4; ++n) {
        const float4* vrow = (const float4*)(vp + (size_t)(n * 16 + m) * 128);
        #pragma unroll
        for (int kk = 0; kk < 4; ++kk) {
            const float4 lo = vrow[(kk * 4 + q4) * 2];
            const float4 hi = vrow[(kk * 4 + q4) * 2 + 1];
            bfv[n][kk] = pack_bf16(lo, hi);
        }
    }

    // per-lane scales for its 16 b's
    f32x4 scv[4];
    #pragma unroll
    for (int n = 0; n < 4; ++n) scv[n] = ((const f32x4*)scp)[n * 4 + q4];

    float se = 0.0f, se2 = 0.0f;

    const int wave = (blockIdx.x << 2) | (t >> 6);   // chunk i: wave + i*SG_NWAVES

    float4 aA[8], aB[8];
    unsigned cA[4], cB[4], vmA, vmB;

    SG_ISSUE(aA, cA, vmA, wave);
    #pragma unroll
    for (int p = 0; p < (SG_NITER - 1) / 2; ++p) {
        SG_ISSUE(aB, cB, vmB, wave + (2 * p + 1) * SG_NWAVES);
        SG_PROCESS(aA, cA, vmA);
        SG_ISSUE(aA, cA, vmA, wave + (2 * p + 2) * SG_NWAVES);
        SG_PROCESS(aB, cB, vmB);
    }
    SG_PROCESS(aA, cA, vmA);                          // chunk (SG_NITER-1)

    se  = wave_reduce64(se);
    se2 = wave_reduce64(se2);
    __shared__ float red[4][2];
    if (lane == 0) { red[t >> 6][0] = se; red[t >> 6][1] = se2; }
    __syncthreads();
    if (t < 2) {
        const float s = red[0][t] + red[1][t] + red[2][t] + red[3][t];
        atomicAdd(&acc[(blockIdx.x & (ACC_GROUPS - 1)) * ACC_STRIDE + bank * 2 + t], s);
    }
}

// ---------------- final: positives (direct dots) + closed-form negatives -----
__global__ __launch_bounds__(256) void final_kernel(
    const int* __restrict__ idx,
    const float* __restrict__ m1, const float* __restrict__ m2,
    const float* __restrict__ vraw_t, const float* __restrict__ vraw_s,
    const float* __restrict__ sct, const float* __restrict__ scs,
    const float* __restrict__ acc, float* __restrict__ out)
{
    const int t = threadIdx.x, wave = t >> 6, lane = t & 63, g = lane >> 4, li = lane & 15;
    __shared__ float e1s[64], e2s[64];

    #pragma unroll
    for (int i = 0; i < 4; ++i) {
        const int b = wave * 16 + i * 4 + g;
        const int row = idx[b];
        float dT = dot8bf((const float4*)(m1 + (size_t)row * 128),
                          (const float4*)(vraw_t + (size_t)b * 128), li, 0.f);
        float dS = dot8bf((const float4*)(m2 + (size_t)row * 128),
                          (const float4*)(vraw_s + (size_t)b * 128), li, 0.f);
        dT = group_reduce16(dT);
        dS = group_reduce16(dS);
        if (li == 0) {
            e1s[b] = __expf(dT * sct[b]);
            e2s[b] = __expf(dS * scs[b]);
        }
    }
    __syncthreads();

    if (t < 64) {
        const int b = t;
        const float c = 0.16384f + 1e-7f;
        const float e1p = e1s[b], e2p = e2s[b];

        const float pseT = wave_reduce64(e1p);
        const float pseS = wave_reduce64(e2p);

        float seT_neg = 0.f, se2T_neg = 0.f, seS_neg = 0.f, se2S_neg = 0.f;
        for (int s = 0; s < ACC_GROUPS; ++s) {
            seT_neg  += acc[s * ACC_STRIDE + 0];
            se2T_neg += acc[s * ACC_STRIDE + 1];
            seS_neg  += acc[s * ACC_STRIDE + 2];
            se2S_neg += acc[s * ACC_STRIDE + 3];
        }

        const float zn = (float)PTOT / (float)NDATA;
        const float invZt = zn / (seT_neg + pseT);   // Z-sum includes positives
        const float invZs = zn / (seS_neg + pseS);

        const float PB = (float)(PTOT - BSZ);        // 1,048,576
        const float LOG_MPN_C = -6.1035156e-7f;      // ln(mPn / (mPn + 1e-7))
        const float ic = 1.0f / c;

        const float negT = PB * LOG_MPN_C
                         - seT_neg * invZt * ic
                         + 0.5f * se2T_neg * invZt * invZt * ic * ic;
        const float negS = PB * LOG_MPN_C
                         - seS_neg * invZs * ic
                         + 0.5f * se2S_neg * invZs * invZs * ic * ic;

        const float x0t = e1p * invZt, x0s = e2p * invZs;
        float pos = __logf(x0t / (x0t + c)) + __logf(x0s / (x0s + c));
        pos = wave_reduce64(pos);

        if (b == 0) out[0] = -(negT + negS + pos) * (1.0f / 64.0f);
    }
}

extern "C" void kernel_launch(void* const* d_in, const int* in_sizes, int n_in,
                              void* d_out, int out_size, void* d_ws, size_t ws_size,
                              hipStream_t stream) {
    const float* fs   = (const float*)d_in[0];
    const float* ft   = (const float*)d_in[1];
    const int*   idx  = (const int*)d_in[2];
    const int*   cidx = (const int*)d_in[3];
    const float* Ws   = (const float*)d_in[4];
    const float* bs   = (const float*)d_in[5];
    const float* Wt   = (const float*)d_in[6];
    const float* bt   = (const float*)d_in[7];
    const float* m1   = (const float*)d_in[8];
    const float* m2   = (const float*)d_in[9];
    float* out = (float*)d_out;

    // ws layout (float index):
    //   [0..64)              sct
    //   [64..128)            scs
    //   [128..2176)          acc (32 groups x 64-float line; 4 used per group)
    //   [2176..4096)         pad
    //   [4096..1604096)      cnt (100000 rows x 16 u32 = 64 B/row, 6.4 MB)
    //   [1604096..1612288)   vraw_s
    //   [1612288..1620480)   vraw_t
    float* ws     = (float*)d_ws;
    float* sct    = ws;
    float* scs    = ws + 64;
    float* acc    = ws + 128;
    unsigned* cnt = (unsigned*)(ws + 4096);
    float* vraw_s = ws + 1604096;
    float* vraw_t = ws + 1612288;

    // zero acc + cnt (sct/scs/vraw fully overwritten)
    hipMemsetAsync(ws + 128, 0, (size_t)(1604096 - 128) * sizeof(float), stream);

    embed_kernel<<<dim3(32, 32), dim3(256), 0, stream>>>(
        fs, ft, Ws, bs, Wt, bt, vraw_s, vraw_t);
    norm_kernel<<<dim3(2), dim3(256), 0, stream>>>(
        vraw_t, vraw_s, sct, scs);
    hist_kernel<<<dim3(64, 16), dim3(256), 0, stream>>>(
        cidx, cnt);
    sgemm_kernel<<<dim3(256, 2), dim3(256), 0, stream>>>(   // grid MUST match SG_NWAVES
        m1, m2, vraw_s, vraw_t, sct, scs, cnt, acc);
    final_kernel<<<dim3(1), dim3(256), 0, stream>>>(
        idx, m1, m2, vraw_t, vraw_s, sct, scs, acc, out);
}